// Round 1
// baseline (432.825 us; speedup 1.0000x reference)
//
#include <hip/hip_runtime.h>

// CRF NLL on MI355X.
// B=64 chains, S=512 steps, T=64 tags (incl START=62, END=63).
// Forward recurrence rewritten in linear domain:
//   q'_j = (sum_i q_i * E_ij) * exp(f_t[j]),  E = exp(trans) precomputed,
//   part_j = ln(q_j) + M0 + esum*ln2  (exact power-of-2 renormalization).
// One block (one wave) per chain: lane j owns tag column j (E column in VGPRs),
// q broadcast via LDS b128 reads. Fixed 512-step loop with uniform (t<L) select.

#define BB 64
#define SS 512
#define TT 64
#define START_TAG 62
#define END_TAG 63
#define LOG2E_F 1.44269504088896340736f
#define LN2_F 0.69314718055994530942f

__global__ __launch_bounds__(64, 1)
void crf_chain_kernel(const float* __restrict__ feats,
                      const float* __restrict__ trans,
                      const int* __restrict__ mask,
                      const int* __restrict__ tags,
                      float* __restrict__ ws) {
    const int b = blockIdx.x;
    const int l = threadIdx.x;  // lane = tag index j

    __shared__ float4 lds_q[TT / 4];  // q vector, read as float4 broadcasts

    const float* fb   = feats + (size_t)b * SS * TT;
    const int*   tagb = tags + b * SS;
    const int*   mkb  = mask + b * SS;

    // ---- E column for this lane: Ecol[i] = exp(trans[i][l]) (64 VGPRs) ----
    float Ecol[TT];
    float t_start = 0.f;  // trans[START][l], raw
    #pragma unroll
    for (int i = 0; i < TT; ++i) {
        float tv = trans[i * TT + l];
        if (i == START_TAG) t_start = tv;
        Ecol[i] = expf(tv);
    }

    // ---- sequence length L (uniform per block; contiguous-prefix mask) ----
    int msum = 0;
    #pragma unroll
    for (int k = 0; k < SS / 64; ++k) msum += mkb[k * 64 + l];
    #pragma unroll
    for (int s_ = 1; s_ < 64; s_ <<= 1) msum += __shfl_xor(msum, s_, 64);
    const int L = msum;

    // ---- gold score (gather-sum, 8 rounds) ----
    float gacc = 0.f;
    #pragma unroll
    for (int k = 0; k < SS / 64; ++k) {
        int t = k * 64 + l;
        int cur  = tagb[t];
        int prev = (t == 0) ? START_TAG : tagb[t - 1];
        float em = fb[t * TT + cur];
        float tr = trans[prev * TT + cur];
        if (t < L) gacc += em + tr;
    }
    if (l == 0) {
        int last = tagb[L - 1];
        gacc += trans[last * TT + END_TAG];
    }
    #pragma unroll
    for (int s_ = 1; s_ < 64; s_ <<= 1) gacc += __shfl_xor(gacc, s_, 64);
    // gacc now holds the full gold score on every lane

    // ---- init: part0_j = f0[j] + trans[START][j]; normalize to q ----
    float part0 = fb[l] + t_start;
    float M0 = part0;
    #pragma unroll
    for (int s_ = 1; s_ < 64; s_ <<= 1) M0 = fmaxf(M0, __shfl_xor(M0, s_, 64));
    float qcur = exp2f((part0 - M0) * LOG2E_F);
    ((float*)lds_q)[l] = qcur;
    __syncthreads();

    int esum = 0;  // accumulated power-of-2 renormalization exponents (uniform)

    // ---- f prefetch pipeline, depth 4 (t = 1..4) ----
    float fpre[4];
    #pragma unroll
    for (int k = 0; k < 4; ++k) fpre[k] = fb[(1 + k) * TT + l];

    // ---- main scan: fixed 512 steps (t = 1..512; t==512 always masked off) ----
    for (int it = 0; it < SS / 4; ++it) {
        #pragma unroll
        for (int k = 0; k < 4; ++k) {
            const int t = 1 + it * 4 + k;
            float fcur = fpre[k];
            int tn = t + 4; tn = (tn < SS) ? tn : (SS - 1);  // clamped prefetch
            fpre[k] = fb[tn * TT + l];

            // matvec: dot_j = sum_i q_i * E[i][j]; 4 accumulators for ILP
            float d0 = 0.f, d1 = 0.f, d2 = 0.f, d3 = 0.f;
            #pragma unroll
            for (int m = 0; m < TT / 4; ++m) {
                float4 q4 = lds_q[m];  // same addr all lanes -> broadcast
                d0 = fmaf(q4.x, Ecol[4 * m + 0], d0);
                d1 = fmaf(q4.y, Ecol[4 * m + 1], d1);
                d2 = fmaf(q4.z, Ecol[4 * m + 2], d2);
                d3 = fmaf(q4.w, Ecol[4 * m + 3], d3);
            }
            float dot = (d0 + d1) + (d2 + d3);

            float qn = dot * exp2f(fcur * LOG2E_F);
            qn = (t < L) ? qn : qcur;  // masked step: keep old q (uniform pred)

            // exact power-of-2 renormalization: bring max(q) into [1,2)
            float M = qn;
            #pragma unroll
            for (int s_ = 1; s_ < 64; s_ <<= 1) M = fmaxf(M, __shfl_xor(M, s_, 64));
            int e = (int)((__float_as_uint(M) >> 23) & 255u) - 127;
            float scale = __uint_as_float((unsigned)(127 - e) << 23);  // 2^-e
            qn *= scale;   // exact
            esum += e;     // uniform across lanes

            qcur = qn;
            ((float*)lds_q)[l] = qn;
            __syncthreads();
        }
    }

    // ---- finalize: transition into END ----
    float d0 = 0.f, d1 = 0.f, d2 = 0.f, d3 = 0.f;
    #pragma unroll
    for (int m = 0; m < TT / 4; ++m) {
        float4 q4 = lds_q[m];
        d0 = fmaf(q4.x, Ecol[4 * m + 0], d0);
        d1 = fmaf(q4.y, Ecol[4 * m + 1], d1);
        d2 = fmaf(q4.z, Ecol[4 * m + 2], d2);
        d3 = fmaf(q4.w, Ecol[4 * m + 3], d3);
    }
    float dotf = (d0 + d1) + (d2 + d3);
    float fwd = logf(dotf) + M0 + (float)esum * LN2_F;  // valid on lane END
    fwd = __shfl(fwd, END_TAG, 64);

    if (l == 0) ws[b] = fwd - gacc;  // per-chain (forward - gold)
}

__global__ __launch_bounds__(64, 1)
void crf_reduce_kernel(const float* __restrict__ ws, float* __restrict__ out) {
    int l = threadIdx.x;
    float v = ws[l];
    #pragma unroll
    for (int s_ = 1; s_ < 64; s_ <<= 1) v += __shfl_xor(v, s_, 64);
    if (l == 0) out[0] = v;
}

extern "C" void kernel_launch(void* const* d_in, const int* in_sizes, int n_in,
                              void* d_out, int out_size, void* d_ws, size_t ws_size,
                              hipStream_t stream) {
    const float* feats = (const float*)d_in[0];
    const float* trans = (const float*)d_in[1];
    const int*   mask  = (const int*)d_in[2];
    const int*   tags  = (const int*)d_in[3];
    float* ws  = (float*)d_ws;
    float* out = (float*)d_out;

    crf_chain_kernel<<<dim3(BB), dim3(64), 0, stream>>>(feats, trans, mask, tags, ws);
    crf_reduce_kernel<<<dim3(1), dim3(64), 0, stream>>>(ws, out);
}

// Round 2
// 237.034 us; speedup vs baseline: 1.8260x; 1.8260x over previous
//
#include <hip/hip_runtime.h>

// CRF NLL on MI355X — round 2.
// Linear-domain forward recurrence, one wave per chain (lane = tag column).
//   q'_j = (sum_i q_i * E_ij) * e^{f_j} * 2^{-e_prev},  E = exp(trans).
// Renorm via lane-0 exponent feedback (readfirstlane, 1-step delayed, exact
// power-of-2 bookkeeping in integer esum) — no per-step wave-max, no barrier.
// Emission exp computed 4+ steps ahead (load pipeline depth 8) off the chain.

#define BB 64
#define SS 512
#define TT 64
#define START_TAG 62
#define END_TAG 63
#define LOG2E_F 1.44269504088896340736f
#define LN2_F 0.69314718055994530942f

typedef float v2f __attribute__((ext_vector_type(2)));
typedef float v4f __attribute__((ext_vector_type(4)));

__global__ __launch_bounds__(64, 1)
void crf_chain_kernel(const float* __restrict__ feats,
                      const float* __restrict__ trans,
                      const int* __restrict__ mask,
                      const int* __restrict__ tags,
                      float* __restrict__ ws) {
    const int b = blockIdx.x;
    const int l = threadIdx.x;  // lane = tag column j

    __shared__ __align__(16) float lds_q[TT];

    const float* fb   = feats + (size_t)b * SS * TT;
    const int*   tagb = tags + b * SS;
    const int*   mkb  = mask + b * SS;

    // ---- E column for this lane, packed as 32 x v2f: Ec[i] = exp(trans[2i..2i+1][l]) ----
    v2f Ec[TT / 2];
    #pragma unroll
    for (int i = 0; i < TT / 2; ++i) {
        float a = trans[(2 * i) * TT + l];
        float c = trans[(2 * i + 1) * TT + l];
        v2f e2; e2[0] = expf(a); e2[1] = expf(c);
        Ec[i] = e2;
    }
    const float t_start = trans[START_TAG * TT + l];

    // ---- sequence length L (contiguous-prefix mask; uniform per block) ----
    int msum = 0;
    #pragma unroll
    for (int k = 0; k < SS / 64; ++k) msum += mkb[k * 64 + l];
    #pragma unroll
    for (int s_ = 1; s_ < 64; s_ <<= 1) msum += __shfl_xor(msum, s_, 64);
    const int L = msum;

    // ---- gold score ----
    float gacc = 0.f;
    #pragma unroll
    for (int k = 0; k < SS / 64; ++k) {
        int t = k * 64 + l;
        int cur  = tagb[t];
        int prev = (t == 0) ? START_TAG : tagb[t - 1];
        float em = fb[t * TT + cur];
        float tr = trans[prev * TT + cur];
        if (t < L) gacc += em + tr;
    }
    if (l == 0) gacc += trans[tagb[L - 1] * TT + END_TAG];
    #pragma unroll
    for (int s_ = 1; s_ < 64; s_ <<= 1) gacc += __shfl_xor(gacc, s_, 64);

    // ---- init: part0 = f0 + trans[START]; one-time wave max; q0 = exp(part0 - M0) ----
    float part0 = fb[l] + t_start;
    float M0 = part0;
    #pragma unroll
    for (int s_ = 1; s_ < 64; s_ <<= 1) M0 = fmaxf(M0, __shfl_xor(M0, s_, 64));
    float q0 = exp2f((part0 - M0) * LOG2E_F);
    lds_q[l] = q0;  // single wave: LDS ops complete in order, no barrier needed

    int   esum = 0;     // exact power-of-2 scales applied so far
    int   e_prev = 0;   // exponent feedback (1-step delayed)
    float sc_prev = 1.0f;

    // ---- emission pipeline: empre[k] = e^{f_{t+k}} ready; fpre[k] = raw f_{t+4+k} in flight ----
    float empre[4], fpre[4];
    #pragma unroll
    for (int k = 0; k < 4; ++k) {
        empre[k] = exp2f(fb[(1 + k) * TT + l] * LOG2E_F);
        int tp = 5 + k; tp = tp < SS ? tp : SS - 1;
        fpre[k] = fb[tp * TT + l];
    }

    const v4f* qv = (const v4f*)lds_q;

#define CRF_STEP(K, TCUR)                                                      \
    {                                                                          \
        float em = empre[K] * sc_prev;                                         \
        esum += e_prev;                                                        \
        /* rotate emission pipeline: exp of f loaded 4 steps ago, load t+8 */  \
        empre[K] = exp2f(fpre[K] * LOG2E_F);                                   \
        int tn = (TCUR) + 8; tn = tn < SS ? tn : SS - 1;                       \
        fpre[K] = fb[tn * TT + l];                                             \
        /* matvec: dot_j = sum_i q_i * E[i][j], 8 packed-FMA chains */         \
        v2f a0 = {0.f, 0.f}, a1 = {0.f, 0.f}, a2 = {0.f, 0.f}, a3 = {0.f, 0.f};\
        _Pragma("unroll")                                                      \
        for (int m = 0; m < 16; m += 2) {                                      \
            v4f qa = qv[m];                                                    \
            v4f qb = qv[m + 1];                                                \
            v2f qa0 = {qa.x, qa.y}, qa1 = {qa.z, qa.w};                        \
            v2f qb0 = {qb.x, qb.y}, qb1 = {qb.z, qb.w};                        \
            a0 = __builtin_elementwise_fma(qa0, Ec[2 * m + 0], a0);            \
            a1 = __builtin_elementwise_fma(qa1, Ec[2 * m + 1], a1);            \
            a2 = __builtin_elementwise_fma(qb0, Ec[2 * m + 2], a2);            \
            a3 = __builtin_elementwise_fma(qb1, Ec[2 * m + 3], a3);            \
        }                                                                      \
        v2f sv = (a0 + a1) + (a2 + a3);                                        \
        float dot = sv[0] + sv[1];                                             \
        float qn = dot * em;                                                   \
        /* lane-0 exponent feedback (off critical path) */                     \
        unsigned u = (unsigned)__builtin_amdgcn_readfirstlane((int)__float_as_uint(qn)); \
        int e = (int)((u >> 23) & 255u) - 127;                                 \
        e = e < -32 ? -32 : (e > 32 ? 32 : e);                                 \
        e_prev = e;                                                            \
        sc_prev = __uint_as_float((unsigned)(127 - e) << 23);                  \
        lds_q[l] = qn;                                                         \
    }

    int t = 1;
    for (; t + 3 < L; t += 4) {
        CRF_STEP(0, t)
        CRF_STEP(1, t + 1)
        CRF_STEP(2, t + 2)
        CRF_STEP(3, t + 3)
    }
    // tail (0..3 steps); pipeline holds em for steps t, t+1, t+2 in slots 0,1,2
    if (t < L) { CRF_STEP(0, t) ++t; }
    if (t < L) { CRF_STEP(1, t) ++t; }
    if (t < L) { CRF_STEP(2, t) ++t; }

    // ---- final transition into END ----
    {
        v2f a0 = {0.f, 0.f}, a1 = {0.f, 0.f}, a2 = {0.f, 0.f}, a3 = {0.f, 0.f};
        #pragma unroll
        for (int m = 0; m < 16; m += 2) {
            v4f qa = qv[m];
            v4f qb = qv[m + 1];
            v2f qa0 = {qa.x, qa.y}, qa1 = {qa.z, qa.w};
            v2f qb0 = {qb.x, qb.y}, qb1 = {qb.z, qb.w};
            a0 = __builtin_elementwise_fma(qa0, Ec[2 * m + 0], a0);
            a1 = __builtin_elementwise_fma(qa1, Ec[2 * m + 1], a1);
            a2 = __builtin_elementwise_fma(qb0, Ec[2 * m + 2], a2);
            a3 = __builtin_elementwise_fma(qb1, Ec[2 * m + 3], a3);
        }
        v2f sv = (a0 + a1) + (a2 + a3);
        float dotf = sv[0] + sv[1];
        float fwd = logf(dotf) + M0 + (float)esum * LN2_F;  // valid on lane END
        fwd = __shfl(fwd, END_TAG, 64);
        if (l == 0) ws[b] = fwd - gacc;
    }
#undef CRF_STEP
}

__global__ __launch_bounds__(64, 1)
void crf_reduce_kernel(const float* __restrict__ ws, float* __restrict__ out) {
    int l = threadIdx.x;
    float v = ws[l];
    #pragma unroll
    for (int s_ = 1; s_ < 64; s_ <<= 1) v += __shfl_xor(v, s_, 64);
    if (l == 0) out[0] = v;
}

extern "C" void kernel_launch(void* const* d_in, const int* in_sizes, int n_in,
                              void* d_out, int out_size, void* d_ws, size_t ws_size,
                              hipStream_t stream) {
    const float* feats = (const float*)d_in[0];
    const float* trans = (const float*)d_in[1];
    const int*   mask  = (const int*)d_in[2];
    const int*   tags  = (const int*)d_in[3];
    float* ws  = (float*)d_ws;
    float* out = (float*)d_out;

    crf_chain_kernel<<<dim3(BB), dim3(64), 0, stream>>>(feats, trans, mask, tags, ws);
    crf_reduce_kernel<<<dim3(1), dim3(64), 0, stream>>>(ws, out);
}

// Round 3
// 223.621 us; speedup vs baseline: 1.9355x; 1.0600x over previous
//
#include <hip/hip_runtime.h>

// CRF NLL on MI355X — round 3.
// Linear-domain forward scan, one wave per chain (lane = tag column).
//   q'_j = (sum_i q_i * E_ij) * e^{f_j} * 2^{-e_prev},  E = exp(trans).
// Round-3 change: steady-state steps contain NO global loads and NO exp —
// raw f loaded in batches of 8 (one vmcnt drain per group, issued a full
// group ahead), exps computed at group boundaries. Final reduction folded
// into the chain kernel via atomicAdd (zero kernel first).

#define BB 64
#define SS 512
#define TT 64
#define START_TAG 62
#define END_TAG 63
#define LOG2E_F 1.44269504088896340736f
#define LN2_F 0.69314718055994530942f

typedef float v2f __attribute__((ext_vector_type(2)));
typedef float v4f __attribute__((ext_vector_type(4)));

__global__ void zero_out_kernel(float* __restrict__ out) { out[0] = 0.f; }

__global__ __launch_bounds__(64, 1)
void crf_chain_kernel(const float* __restrict__ feats,
                      const float* __restrict__ trans,
                      const int* __restrict__ mask,
                      const int* __restrict__ tags,
                      float* __restrict__ out) {
    const int b = blockIdx.x;
    const int l = threadIdx.x;  // lane = tag column j

    __shared__ __align__(16) float lds_q[TT];

    const float* fb   = feats + (size_t)b * SS * TT;
    const int*   tagb = tags + b * SS;
    const int*   mkb  = mask + b * SS;

    // ---- E column for this lane, packed: Ec[i] = exp(trans[2i..2i+1][l]) ----
    v2f Ec[TT / 2];
    #pragma unroll
    for (int i = 0; i < TT / 2; ++i) {
        v2f e2;
        e2[0] = expf(trans[(2 * i) * TT + l]);
        e2[1] = expf(trans[(2 * i + 1) * TT + l]);
        Ec[i] = e2;
    }
    const float t_start = trans[START_TAG * TT + l];

    // ---- sequence length L (contiguous-prefix mask; uniform per block) ----
    int msum = 0;
    #pragma unroll
    for (int k = 0; k < SS / 64; ++k) msum += mkb[k * 64 + l];
    #pragma unroll
    for (int s_ = 1; s_ < 64; s_ <<= 1) msum += __shfl_xor(msum, s_, 64);
    const int L = msum;

    // ---- gold score ----
    float gacc = 0.f;
    #pragma unroll
    for (int k = 0; k < SS / 64; ++k) {
        int t = k * 64 + l;
        int cur  = tagb[t];
        int prev = (t == 0) ? START_TAG : tagb[t - 1];
        float em = fb[t * TT + cur];
        float tr = trans[prev * TT + cur];
        if (t < L) gacc += em + tr;
    }
    if (l == 0) gacc += trans[tagb[L - 1] * TT + END_TAG];
    #pragma unroll
    for (int s_ = 1; s_ < 64; s_ <<= 1) gacc += __shfl_xor(gacc, s_, 64);

    // ---- init: part0 = f0 + trans[START]; one-time wave max; q0 ----
    float part0 = fb[l] + t_start;
    float M0 = part0;
    #pragma unroll
    for (int s_ = 1; s_ < 64; s_ <<= 1) M0 = fmaxf(M0, __shfl_xor(M0, s_, 64));
    float q0 = exp2f((part0 - M0) * LOG2E_F);
    lds_q[l] = q0;  // single wave: no barrier needed

    int   esum = 0;     // sum of applied power-of-2 scales (exact)
    int   e_prev = 0;   // exponent feedback (1-step delayed)
    float sc_prev = 1.0f;

    const v4f* qv = (const v4f*)lds_q;

    // ---- raw-f pipeline: fraw[k] holds f[t+k] for the UPCOMING group ----
    float fraw[8], em8[8];
    #pragma unroll
    for (int k = 0; k < 8; ++k) {
        int tp = 1 + k; tp = tp < SS ? tp : SS - 1;
        fraw[k] = fb[tp * TT + l];
    }

#define CRF_STEP(K)                                                            \
    {                                                                          \
        float em = em8[K] * sc_prev;                                           \
        esum += e_prev;                                                        \
        v2f a0 = {0.f, 0.f}, a1 = {0.f, 0.f}, a2 = {0.f, 0.f}, a3 = {0.f, 0.f};\
        _Pragma("unroll")                                                      \
        for (int m = 0; m < 16; m += 2) {                                      \
            v4f qa = qv[m];                                                    \
            v4f qb = qv[m + 1];                                                \
            v2f qa0 = {qa.x, qa.y}, qa1 = {qa.z, qa.w};                        \
            v2f qb0 = {qb.x, qb.y}, qb1 = {qb.z, qb.w};                        \
            a0 = __builtin_elementwise_fma(qa0, Ec[2 * m + 0], a0);            \
            a1 = __builtin_elementwise_fma(qa1, Ec[2 * m + 1], a1);            \
            a2 = __builtin_elementwise_fma(qb0, Ec[2 * m + 2], a2);            \
            a3 = __builtin_elementwise_fma(qb1, Ec[2 * m + 3], a3);            \
        }                                                                      \
        v2f sv = (a0 + a1) + (a2 + a3);                                        \
        float dot = sv[0] + sv[1];                                             \
        float qn = dot * em;                                                   \
        lds_q[l] = qn;                                                         \
        unsigned u = (unsigned)__builtin_amdgcn_readfirstlane((int)__float_as_uint(qn)); \
        int e = (int)((u >> 23) & 255u) - 127;                                 \
        e_prev = e;                                                            \
        sc_prev = __uint_as_float((unsigned)(127 - e) << 23);                  \
    }

    int t = 1;
    for (; t + 7 < L; t += 8) {
        // consume last group's loads (single amortized vmcnt drain), make exps
        #pragma unroll
        for (int k = 0; k < 8; ++k) em8[k] = exp2f(fraw[k] * LOG2E_F);
        // issue next group's loads (consumed >= 8 steps from now)
        #pragma unroll
        for (int k = 0; k < 8; ++k) {
            int tn = t + 8 + k; tn = tn < SS ? tn : SS - 1;
            fraw[k] = fb[tn * TT + l];
        }
        CRF_STEP(0) CRF_STEP(1) CRF_STEP(2) CRF_STEP(3)
        CRF_STEP(4) CRF_STEP(5) CRF_STEP(6) CRF_STEP(7)
    }
    // tail: <= 7 remaining steps
    {
        #pragma unroll
        for (int k = 0; k < 8; ++k) em8[k] = exp2f(fraw[k] * LOG2E_F);
        if (t < L) { CRF_STEP(0) ++t; }
        if (t < L) { CRF_STEP(1) ++t; }
        if (t < L) { CRF_STEP(2) ++t; }
        if (t < L) { CRF_STEP(3) ++t; }
        if (t < L) { CRF_STEP(4) ++t; }
        if (t < L) { CRF_STEP(5) ++t; }
        if (t < L) { CRF_STEP(6) ++t; }
    }
#undef CRF_STEP

    // ---- final transition into END ----
    {
        v2f a0 = {0.f, 0.f}, a1 = {0.f, 0.f}, a2 = {0.f, 0.f}, a3 = {0.f, 0.f};
        #pragma unroll
        for (int m = 0; m < 16; m += 2) {
            v4f qa = qv[m];
            v4f qb = qv[m + 1];
            v2f qa0 = {qa.x, qa.y}, qa1 = {qa.z, qa.w};
            v2f qb0 = {qb.x, qb.y}, qb1 = {qb.z, qb.w};
            a0 = __builtin_elementwise_fma(qa0, Ec[2 * m + 0], a0);
            a1 = __builtin_elementwise_fma(qa1, Ec[2 * m + 1], a1);
            a2 = __builtin_elementwise_fma(qb0, Ec[2 * m + 2], a2);
            a3 = __builtin_elementwise_fma(qb1, Ec[2 * m + 3], a3);
        }
        v2f sv = (a0 + a1) + (a2 + a3);
        float dotf = sv[0] + sv[1];
        float fwd = logf(dotf) + M0 + (float)esum * LN2_F;  // valid on lane END
        fwd = __shfl(fwd, END_TAG, 64);
        if (l == 0) atomicAdd(out, fwd - gacc);
    }
}

extern "C" void kernel_launch(void* const* d_in, const int* in_sizes, int n_in,
                              void* d_out, int out_size, void* d_ws, size_t ws_size,
                              hipStream_t stream) {
    const float* feats = (const float*)d_in[0];
    const float* trans = (const float*)d_in[1];
    const int*   mask  = (const int*)d_in[2];
    const int*   tags  = (const int*)d_in[3];
    float* out = (float*)d_out;

    zero_out_kernel<<<dim3(1), dim3(1), 0, stream>>>(out);
    crf_chain_kernel<<<dim3(BB), dim3(64), 0, stream>>>(feats, trans, mask, tags, out);
}

// Round 4
// 193.683 us; speedup vs baseline: 2.2347x; 1.1546x over previous
//
#include <hip/hip_runtime.h>

// CRF NLL on MI355X — round 4.
// One chain per block, but each step's 64x64 matvec split across 4 waves:
//   wave w owns output tags j in [16w,16w+16); quad-lane sub covers i in [16sub,16sub+16).
// Per lane per step: 4 ds_read_b128 + 8 pk-FMA + 2 quad shfl_xor (DPP) + write.
// Double-buffered q in LDS, ONE barrier per step. Exact power-of-2 renorm read
// from q[P][0] (broadcast), zero-delay, fp32 throughout (no precision loss).
// Global f loads issued once per 8-step group right after a barrier (drain
// lands on the following barrier ~250cyc later => amortized ~free).

#define BB 64
#define SS 512
#define TT 64
#define START_TAG 62
#define END_TAG 63
#define LOG2E_F 1.44269504088896340736f
#define LN2_F 0.69314718055994530942f

typedef float v2f __attribute__((ext_vector_type(2)));
typedef float v4f __attribute__((ext_vector_type(4)));

__global__ void zero_out_kernel(float* __restrict__ out) { out[0] = 0.f; }

__global__ __launch_bounds__(256, 1)
void crf_chain_kernel(const float* __restrict__ feats,
                      const float* __restrict__ trans,
                      const int* __restrict__ mask,
                      const int* __restrict__ tags,
                      float* __restrict__ out) {
    const int b   = blockIdx.x;
    const int tid = threadIdx.x;
    const int w   = tid >> 6;        // wave 0..3
    const int l   = tid & 63;        // lane in wave
    const int sub = l & 3;           // quad sub-lane: input range [16sub, 16sub+16)
    const int jl  = (w << 4) | (l >> 2);  // output tag owned by this quad

    __shared__ __align__(16) float q[2][TT];   // double-buffered q vector

    const float* fb   = feats + (size_t)b * SS * TT;
    const int*   tagb = tags + b * SS;
    const int*   mkb  = mask + b * SS;

    // ---- E slice: Ep[m] = (exp(trans[i0+2m][jl]), exp(trans[i0+2m+1][jl])), i0=16sub ----
    v2f Ep[8];
    {
        const int i0 = 16 * sub;
        #pragma unroll
        for (int m = 0; m < 8; ++m) {
            v2f e2;
            e2[0] = expf(trans[(i0 + 2 * m) * TT + jl]);
            e2[1] = expf(trans[(i0 + 2 * m + 1) * TT + jl]);
            Ep[m] = e2;
        }
    }

    // ---- sequence length L (uniform per block; each wave computes it) ----
    int msum = 0;
    #pragma unroll
    for (int k = 0; k < SS / 64; ++k) msum += mkb[k * 64 + l];
    #pragma unroll
    for (int s_ = 1; s_ < 64; s_ <<= 1) msum += __shfl_xor(msum, s_, 64);
    const int L = msum;

    // ---- gold score + init q0 (wave 0 only) ----
    float gacc = 0.f;
    float M0 = 0.f;
    if (w == 0) {
        #pragma unroll
        for (int k = 0; k < SS / 64; ++k) {
            int t = k * 64 + l;
            int cur  = tagb[t];
            int prev = (t == 0) ? START_TAG : tagb[t - 1];
            float em = fb[t * TT + cur];
            float tr = trans[prev * TT + cur];
            if (t < L) gacc += em + tr;
        }
        if (l == 0) gacc += trans[tagb[L - 1] * TT + END_TAG];
        #pragma unroll
        for (int s_ = 1; s_ < 64; s_ <<= 1) gacc += __shfl_xor(gacc, s_, 64);

        float part0 = fb[l] + trans[START_TAG * TT + l];
        M0 = part0;
        #pragma unroll
        for (int s_ = 1; s_ < 64; s_ <<= 1) M0 = fmaxf(M0, __shfl_xor(M0, s_, 64));
        q[0][l] = exp2f((part0 - M0) * LOG2E_F);
    }

    // ---- raw-f preload for first group (steps 1..8) ----
    float fraw[8];
    #pragma unroll
    for (int k = 0; k < 8; ++k) {
        int tp = 1 + k; tp = tp < SS ? tp : SS - 1;
        fraw[k] = fb[tp * TT + jl];
    }

    __syncthreads();

    int esum = 0;

#define CRF_STEP(K, P)                                                         \
    {                                                                          \
        float qref = q[P][0];                                                  \
        const v4f* qv = (const v4f*)q[P];                                      \
        v4f r0 = qv[4 * sub + 0];                                              \
        v4f r1 = qv[4 * sub + 1];                                              \
        v4f r2 = qv[4 * sub + 2];                                              \
        v4f r3 = qv[4 * sub + 3];                                              \
        float em = exp2f(fcur[K] * LOG2E_F);                                   \
        v2f a0 = {0.f, 0.f}, a1 = {0.f, 0.f};                                  \
        v2f p;                                                                 \
        p[0] = r0.x; p[1] = r0.y; a0 = __builtin_elementwise_fma(p, Ep[0], a0);\
        p[0] = r0.z; p[1] = r0.w; a1 = __builtin_elementwise_fma(p, Ep[1], a1);\
        p[0] = r1.x; p[1] = r1.y; a0 = __builtin_elementwise_fma(p, Ep[2], a0);\
        p[0] = r1.z; p[1] = r1.w; a1 = __builtin_elementwise_fma(p, Ep[3], a1);\
        p[0] = r2.x; p[1] = r2.y; a0 = __builtin_elementwise_fma(p, Ep[4], a0);\
        p[0] = r2.z; p[1] = r2.w; a1 = __builtin_elementwise_fma(p, Ep[5], a1);\
        p[0] = r3.x; p[1] = r3.y; a0 = __builtin_elementwise_fma(p, Ep[6], a0);\
        p[0] = r3.z; p[1] = r3.w; a1 = __builtin_elementwise_fma(p, Ep[7], a1);\
        v2f sv = a0 + a1;                                                      \
        float s = sv[0] + sv[1];                                               \
        s += __shfl_xor(s, 1, 64);                                             \
        s += __shfl_xor(s, 2, 64);                                             \
        unsigned u = __float_as_uint(qref);                                    \
        int e = (int)((u >> 23) & 255u) - 127;                                 \
        esum += e;                                                             \
        float sc = __uint_as_float((unsigned)(127 - e) << 23);                 \
        float qn = s * (em * sc);                                              \
        if (sub == 0) q[1 - (P)][jl] = qn;                                     \
        __syncthreads();                                                       \
    }

    int t = 1;
    for (; t + 7 < L; t += 8) {
        float fcur[8];
        #pragma unroll
        for (int k = 0; k < 8; ++k) fcur[k] = fraw[k];
        // issue next group's loads now; they drain at the NEXT barrier (~250cyc away)
        #pragma unroll
        for (int k = 0; k < 8; ++k) {
            int tn = t + 8 + k; tn = tn < SS ? tn : SS - 1;
            fraw[k] = fb[tn * TT + jl];
        }
        CRF_STEP(0, 0) CRF_STEP(1, 1) CRF_STEP(2, 0) CRF_STEP(3, 1)
        CRF_STEP(4, 0) CRF_STEP(5, 1) CRF_STEP(6, 0) CRF_STEP(7, 1)
    }
    // tail: <= 7 steps (L uniform across the block -> barriers remain uniform)
    {
        float fcur[8];
        #pragma unroll
        for (int k = 0; k < 8; ++k) fcur[k] = fraw[k];
        if (t < L) { CRF_STEP(0, 0) ++t; }
        if (t < L) { CRF_STEP(1, 1) ++t; }
        if (t < L) { CRF_STEP(2, 0) ++t; }
        if (t < L) { CRF_STEP(3, 1) ++t; }
        if (t < L) { CRF_STEP(4, 0) ++t; }
        if (t < L) { CRF_STEP(5, 1) ++t; }
        if (t < L) { CRF_STEP(6, 0) ++t; }
    }
#undef CRF_STEP

    // ---- final transition into END: wave 3's quad 15 owns j=63 ----
    if (w == 3) {
        const v4f* qv = (const v4f*)q[(L - 1) & 1];
        v4f r0 = qv[4 * sub + 0];
        v4f r1 = qv[4 * sub + 1];
        v4f r2 = qv[4 * sub + 2];
        v4f r3 = qv[4 * sub + 3];
        v2f a0 = {0.f, 0.f}, a1 = {0.f, 0.f};
        v2f p;
        p[0] = r0.x; p[1] = r0.y; a0 = __builtin_elementwise_fma(p, Ep[0], a0);
        p[0] = r0.z; p[1] = r0.w; a1 = __builtin_elementwise_fma(p, Ep[1], a1);
        p[0] = r1.x; p[1] = r1.y; a0 = __builtin_elementwise_fma(p, Ep[2], a0);
        p[0] = r1.z; p[1] = r1.w; a1 = __builtin_elementwise_fma(p, Ep[3], a1);
        p[0] = r2.x; p[1] = r2.y; a0 = __builtin_elementwise_fma(p, Ep[4], a0);
        p[0] = r2.z; p[1] = r2.w; a1 = __builtin_elementwise_fma(p, Ep[5], a1);
        p[0] = r3.x; p[1] = r3.y; a0 = __builtin_elementwise_fma(p, Ep[6], a0);
        p[0] = r3.z; p[1] = r3.w; a1 = __builtin_elementwise_fma(p, Ep[7], a1);
        v2f sv = a0 + a1;
        float s = sv[0] + sv[1];
        s += __shfl_xor(s, 1, 64);
        s += __shfl_xor(s, 2, 64);
        if (l == 60) atomicAdd(out, logf(s) + (float)esum * LN2_F);  // jl==63, sub==0
    }
    if (w == 0 && l == 0) atomicAdd(out, M0 - gacc);
}

extern "C" void kernel_launch(void* const* d_in, const int* in_sizes, int n_in,
                              void* d_out, int out_size, void* d_ws, size_t ws_size,
                              hipStream_t stream) {
    const float* feats = (const float*)d_in[0];
    const float* trans = (const float*)d_in[1];
    const int*   mask  = (const int*)d_in[2];
    const int*   tags  = (const int*)d_in[3];
    float* out = (float*)d_out;

    zero_out_kernel<<<dim3(1), dim3(1), 0, stream>>>(out);
    crf_chain_kernel<<<dim3(BB), dim3(256), 0, stream>>>(feats, trans, mask, tags, out);
}